// Round 1
// baseline (1047.143 us; speedup 1.0000x reference)
//
#include <hip/hip_runtime.h>

#define NTHREADS 256
#define NB 4        // nodes per block (N=50000 -> 12500 blocks, no tail)
#define K 16
#define KP1 17
#define F 128
#define H 8
#define D 64
#define FP 132      // padded row stride: rows land 4 banks apart; k,k+8 alias = 2-way (free)
#define NEG_SLOPE 0.2f

// LDS: xall 4*17*132*4 = 35904 + attn 4*17*8*4 = 2176 + self 128 = 38208 B -> 4 blocks/CU
// VGPR: __launch_bounds__(256,4) -> <=128 VGPR (4 waves/SIMD, 16 waves/CU)

__global__ __launch_bounds__(NTHREADS, 4) void gat_kernel(
    const float* __restrict__ x_self,   // [N,F]
    const float* __restrict__ x_neigh,  // [N,K,F]
    const float* __restrict__ W,        // [H,F,D]
    const float* __restrict__ a_self,   // [H,F]
    const float* __restrict__ a_neigh,  // [H,F]
    float* __restrict__ out,            // [N,H*D]
    int N)
{
    __shared__ __align__(16) float xall[NB][KP1][FP];   // k=0 is self row; reused as yb after phase 4
    __shared__ __align__(16) float attn[NB][KP1][H];
    __shared__ float self_s[NB][H];

    float* yb = (float*)xall;   // [NB][H][FP] alias, valid after phase-4 second sync

    const int tid = threadIdx.x;
    const int node0 = blockIdx.x * NB;

    // ---- Phase 1: stage x_all into LDS (float4, coalesced) ----
    {
        const int tot_self = NB * (F / 4);              // 128 float4
        for (int i = tid; i < tot_self; i += NTHREADS) {
            int nb = i / (F / 4);
            int f4 = i % (F / 4);
            if (node0 + nb < N) {
                float4 v = ((const float4*)(x_self + (size_t)(node0 + nb) * F))[f4];
                *(float4*)&xall[nb][0][f4 * 4] = v;
            }
        }
        const int tot_n = NB * K * (F / 4);             // 2048 float4
        for (int i = tid; i < tot_n; i += NTHREADS) {
            int nb  = i / (K * F / 4);
            int rem = i % (K * F / 4);
            int k   = rem / (F / 4);
            int f4  = rem % (F / 4);
            if (node0 + nb < N) {
                float4 v = ((const float4*)(x_neigh + ((size_t)(node0 + nb) * K + k) * F))[f4];
                *(float4*)&xall[nb][k + 1][f4 * 4] = v;
            }
        }
    }
    __syncthreads();

    // ---- Phase 2: unified logit dots. 576 tasks = NB * (17*8 neigh-dots + 8 self-dots) ----
    {
        const int TPN = KP1 * H + H;                    // 144 tasks per node
        for (int i = tid; i < NB * TPN; i += NTHREADS) {
            int nb  = i / TPN;
            int rem = i % TPN;
            int k, h;
            const float* av;
            const float* xr;
            bool is_self = (rem >= KP1 * H);
            if (!is_self) {
                k = rem >> 3; h = rem & 7;
                av = a_neigh + h * F;
                xr = &xall[nb][k][0];
            } else {
                k = 0; h = rem - KP1 * H;
                av = a_self + h * F;
                xr = &xall[nb][0][0];
            }
            float4 s = {0.f, 0.f, 0.f, 0.f};
            #pragma unroll 8
            for (int f4 = 0; f4 < F / 4; f4++) {
                float4 xv = *(const float4*)(xr + f4 * 4);
                float4 avv = ((const float4*)av)[f4];
                s.x += xv.x * avv.x; s.y += xv.y * avv.y;
                s.z += xv.z * avv.z; s.w += xv.w * avv.w;
            }
            float dot = (s.x + s.y) + (s.z + s.w);
            if (!is_self) attn[nb][k][h] = dot;
            else          self_s[nb][h] = dot;
        }
    }
    __syncthreads();

    // ---- Phase 3: add self logit, LeakyReLU, exp; store 1/sum in self_s.
    //      Normalization is folded into phase 4 (saves the 3rd 17-iter pass). ----
    for (int i = tid; i < NB * H; i += NTHREADS) {
        int nb = i >> 3, h = i & 7;
        float sl = self_s[nb][h];
        float lg[KP1];
        float m = -1e30f;
        #pragma unroll
        for (int k = 0; k < KP1; k++) {
            float v = sl + attn[nb][k][h];
            v = (v >= 0.f) ? v : NEG_SLOPE * v;
            lg[k] = v;
            m = fmaxf(m, v);
        }
        float s = 0.f;
        #pragma unroll
        for (int k = 0; k < KP1; k++) {
            float e = __expf(lg[k] - m);
            attn[nb][k][h] = e;
            s += e;
        }
        self_s[nb][h] = 1.0f / s;    // reuse as inverse-denominator
    }
    __syncthreads();

    // ---- Phase 4: y[nb][h][f] = inv_s * sum_k e[k,h] * x_all[k][f].
    //      Thread = (f4, nb, head-half): each xall float4 is read ONCE and applied to
    //      4 heads via a single 16B attn vector read (was: 8x redundant full-width reads).
    //      Per-wave xv read: 2 rows x 32 lanes = 128 consecutive floats each -> all 32
    //      banks covered exactly (conflict-free full-bandwidth b128). ----
    {
        const int f4 = tid & 31;         // 0..31
        const int nb = (tid >> 5) & 3;   // 0..3
        const int hh = tid >> 7;         // 0..1 -> heads hh*4 .. hh*4+3
        const float* xb = &xall[nb][0][f4 * 4];
        const float* ab = &attn[nb][0][hh * 4];
        float4 a0 = {0.f,0.f,0.f,0.f}, a1 = a0, a2 = a0, a3 = a0;
        #pragma unroll 4
        for (int k = 0; k < KP1; k++) {
            float4 xv = *(const float4*)(xb + k * FP);
            float4 av = *(const float4*)(ab + k * H);
            a0.x += av.x * xv.x; a0.y += av.x * xv.y; a0.z += av.x * xv.z; a0.w += av.x * xv.w;
            a1.x += av.y * xv.x; a1.y += av.y * xv.y; a1.z += av.y * xv.z; a1.w += av.y * xv.w;
            a2.x += av.z * xv.x; a2.y += av.z * xv.y; a2.z += av.z * xv.z; a2.w += av.z * xv.w;
            a3.x += av.w * xv.x; a3.y += av.w * xv.y; a3.z += av.w * xv.z; a3.w += av.w * xv.w;
        }
        const float i0 = self_s[nb][hh * 4 + 0];
        const float i1 = self_s[nb][hh * 4 + 1];
        const float i2 = self_s[nb][hh * 4 + 2];
        const float i3 = self_s[nb][hh * 4 + 3];
        a0.x *= i0; a0.y *= i0; a0.z *= i0; a0.w *= i0;
        a1.x *= i1; a1.y *= i1; a1.z *= i1; a1.w *= i1;
        a2.x *= i2; a2.y *= i2; a2.z *= i2; a2.w *= i2;
        a3.x *= i3; a3.y *= i3; a3.z *= i3; a3.w *= i3;
        __syncthreads();   // everyone done READING xall
        *(float4*)&yb[((size_t)(nb * H) + hh * 4 + 0) * FP + f4 * 4] = a0;
        *(float4*)&yb[((size_t)(nb * H) + hh * 4 + 1) * FP + f4 * 4] = a1;
        *(float4*)&yb[((size_t)(nb * H) + hh * 4 + 2) * FP + f4 * 4] = a2;
        *(float4*)&yb[((size_t)(nb * H) + hh * 4 + 3) * FP + f4 * 4] = a3;
    }
    __syncthreads();

    // ---- Phase 5: out[nb][h][d] = y[nb][h][:] @ W[h][:][d].
    //      Thread = (d-pair, h): W read exactly once per block, as float2 (halves VMEM
    //      instr count vs scalar); yv read once per (f4,nb) and reused for both d
    //      (halves LDS reads); float2 coalesced stores. h rows of yb are 132 floats
    //      apart -> the wave's 2 distinct broadcast addresses hit different banks. ----
    {
        const int d2 = tid & 31;         // covers d = d2*2, d2*2+1
        const int h  = tid >> 5;         // 0..7
        const float* Wp = W + ((size_t)h * F) * D + d2 * 2;
        const float* y0 = &yb[((size_t)(0 * H) + h) * FP];
        const float* y1 = &yb[((size_t)(1 * H) + h) * FP];
        const float* y2 = &yb[((size_t)(2 * H) + h) * FP];
        const float* y3 = &yb[((size_t)(3 * H) + h) * FP];
        float2 c0 = {0.f,0.f}, c1 = c0, c2 = c0, c3 = c0;
        #pragma unroll 4
        for (int f4 = 0; f4 < F / 4; f4++) {
            float2 w0 = *(const float2*)(Wp + (f4 * 4 + 0) * D);
            float2 w1 = *(const float2*)(Wp + (f4 * 4 + 1) * D);
            float2 w2 = *(const float2*)(Wp + (f4 * 4 + 2) * D);
            float2 w3 = *(const float2*)(Wp + (f4 * 4 + 3) * D);
            float4 v0 = *(const float4*)(y0 + f4 * 4);
            float4 v1 = *(const float4*)(y1 + f4 * 4);
            float4 v2 = *(const float4*)(y2 + f4 * 4);
            float4 v3 = *(const float4*)(y3 + f4 * 4);
            c0.x += v0.x * w0.x + v0.y * w1.x + v0.z * w2.x + v0.w * w3.x;
            c0.y += v0.x * w0.y + v0.y * w1.y + v0.z * w2.y + v0.w * w3.y;
            c1.x += v1.x * w0.x + v1.y * w1.x + v1.z * w2.x + v1.w * w3.x;
            c1.y += v1.x * w0.y + v1.y * w1.y + v1.z * w2.y + v1.w * w3.y;
            c2.x += v2.x * w0.x + v2.y * w1.x + v2.z * w2.x + v2.w * w3.x;
            c2.y += v2.x * w0.y + v2.y * w1.y + v2.z * w2.y + v2.w * w3.y;
            c3.x += v3.x * w0.x + v3.y * w1.x + v3.z * w2.x + v3.w * w3.x;
            c3.y += v3.x * w0.y + v3.y * w1.y + v3.z * w2.y + v3.w * w3.y;
        }
        if (node0 + 0 < N) *(float2*)&out[(size_t)(node0 + 0) * (H * D) + h * D + d2 * 2] = c0;
        if (node0 + 1 < N) *(float2*)&out[(size_t)(node0 + 1) * (H * D) + h * D + d2 * 2] = c1;
        if (node0 + 2 < N) *(float2*)&out[(size_t)(node0 + 2) * (H * D) + h * D + d2 * 2] = c2;
        if (node0 + 3 < N) *(float2*)&out[(size_t)(node0 + 3) * (H * D) + h * D + d2 * 2] = c3;
    }
}

extern "C" void kernel_launch(void* const* d_in, const int* in_sizes, int n_in,
                              void* d_out, int out_size, void* d_ws, size_t ws_size,
                              hipStream_t stream) {
    const float* x_self  = (const float*)d_in[0];
    const float* x_neigh = (const float*)d_in[1];
    const float* W       = (const float*)d_in[2];
    const float* a_self  = (const float*)d_in[3];
    const float* a_neigh = (const float*)d_in[4];
    float* out = (float*)d_out;

    const int N = in_sizes[0] / F;                 // 50000
    const int nblocks = (N + NB - 1) / NB;         // 12500
    gat_kernel<<<nblocks, NTHREADS, 0, stream>>>(x_self, x_neigh, W, a_self, a_neigh, out, N);
}